// Round 9
// baseline (340.569 us; speedup 1.0000x reference)
//
#include <hip/hip_runtime.h>
#include <math.h>
#include <stdint.h>

#define B_ 4
#define T_ 1024
#define NH_ 16
#define MSZ (4194304)   // B*T*1024 elems

typedef float f4 __attribute__((ext_vector_type(4)));
typedef float f32x4 __attribute__((ext_vector_type(4)));
typedef __bf16 bf16x8 __attribute__((ext_vector_type(8)));
typedef __bf16 bf16x4 __attribute__((ext_vector_type(4)));

static __device__ __forceinline__ f32x4 mfma16(bf16x8 a, bf16x8 b, f32x4 c) {
    return __builtin_amdgcn_mfma_f32_16x16x32_bf16(a, b, c, 0, 0, 0);
}

// global -> LDS direct 16B copy (lane l writes dst + l*16)
static __device__ __forceinline__ void gld16(const void* g, void* l) {
    auto gp = reinterpret_cast<const uint32_t __attribute__((address_space(1)))*>(
        reinterpret_cast<uintptr_t>(g));
    auto lp = reinterpret_cast<uint32_t __attribute__((address_space(3)))*>(
        reinterpret_cast<uintptr_t>(l));
    __builtin_amdgcn_global_load_lds(gp, lp, 16, 0, 0);
}

// ---------------------------------------------------------------- zero accum
__global__ void k_zero(float* acc) {
    if (threadIdx.x < 2) acc[threadIdx.x] = 0.f;
}

// ---------------------------------------------------------------- hi/lo bf16 split -> FRAGMENT-TILED layout
// Tile = 16 rows x 32 cols of the source matrix. Stored as 64 lanes x 8 bf16:
//   lane = (colchunk&3)*16 + (row&15), elems = cols [c0*32 + (lane>>4)*8 .. +7]
// so an MFMA A/B fragment load is ONE contiguous 1KB global_load_dwordx4 per wave.
// tiles: data 8192 (256x32) | qkv_w 6144 (192x32) | out_w 2048 (64x32)
__global__ __launch_bounds__(256) void k_split(
        const float* __restrict__ data, __bf16* __restrict__ dH, __bf16* __restrict__ dL,
        const float* __restrict__ w1,   __bf16* __restrict__ w1H, __bf16* __restrict__ w1L,
        const float* __restrict__ w2,   __bf16* __restrict__ w2H, __bf16* __restrict__ w2L)
{
    const int lane = threadIdx.x & 63;
    const int lr = lane & 15, lg = lane >> 4;
    const int wg = (blockIdx.x * 256 + threadIdx.x) >> 6;
    const int nw = (gridDim.x * 256) >> 6;
    for (int t = wg; t < 16384; t += nw) {
        const float* s; __bf16 *H, *L; int tt;
        if (t < 8192)       { s = data; H = dH;  L = dL;  tt = t; }
        else if (t < 14336) { s = w1;   H = w1H; L = w1L; tt = t - 8192; }
        else                { s = w2;   H = w2H; L = w2L; tt = t - 14336; }
        int r0 = tt >> 5, c0 = tt & 31;
        const float* src = s + (size_t)(r0*16 + lr)*1024 + c0*32 + lg*8;
        f4 a = *(const f4*)src;
        f4 b = *(const f4*)(src + 4);
        bf16x8 h, l;
        #pragma unroll
        for (int j = 0; j < 4; ++j) {
            __bf16 h1 = (__bf16)a[j];
            h[j] = h1; l[j] = (__bf16)(a[j] - (float)h1);
            __bf16 h2 = (__bf16)b[j];
            h[4+j] = h2; l[4+j] = (__bf16)(b[j] - (float)h2);
        }
        *(bf16x8*)(H + (size_t)tt*512 + lane*8) = h;
        *(bf16x8*)(L + (size_t)tt*512 + lane*8) = l;
    }
}

// ---------------------------------------------------------------- split-bf16 MFMA GEMM, LDS-free
// C[n,m] = sum_k A[n,k]*W[m,k] + bias[m]; A,W as hi/lo bf16 pairs in FRAGMENT-TILED
// layout. Each fragment is one coalesced 1KB load from L2 (sibling waves L1-hit the
// shared tiles). No LDS, no barriers -> compiler pipelines loads across K freely.
// 3 MFMA passes: al*bh + ah*bl + ah*bh.
// MODE 0 (qkv): M=3072, outputs bf16 Qb/Kb ([bh][t][64]) and Vtb ([bh][d][t]).
// MODE 1 (oproj): M=1024, output f32 [n][m].
template<int MODE>
__global__ __launch_bounds__(256, 2) void k_gemm(
        const __bf16* __restrict__ AH, const __bf16* __restrict__ AL,
        const __bf16* __restrict__ BH, const __bf16* __restrict__ BL,
        const float* __restrict__ bias,
        __bf16* __restrict__ Qb, __bf16* __restrict__ Kb, __bf16* __restrict__ Vtb,
        float* __restrict__ outf)
{
    const int tid  = threadIdx.x;
    const int lane = tid & 63;
    const int wid  = tid >> 6;
    const int lr   = lane & 15;
    const int lg   = lane >> 4;
    const int wr   = wid >> 1, wc = wid & 1;
    const int m0 = blockIdx.x * 128;
    const int n0 = blockIdx.y * 128;
    const int ar0 = (n0 >> 4) + wr*4;   // A row-tile base for this wave
    const int br0 = (m0 >> 4) + wc*4;   // B row-tile base

    f32x4 acc[4][4];
    #pragma unroll
    for (int i = 0; i < 4; ++i)
        #pragma unroll
        for (int j = 0; j < 4; ++j) acc[i][j] = (f32x4){0.f,0.f,0.f,0.f};

    for (int c0 = 0; c0 < 32; ++c0) {   // K=32 per iteration
        bf16x8 ah[4], al[4], bh_[4], bl[4];
        #pragma unroll
        for (int rf = 0; rf < 4; ++rf) {
            size_t o = (((size_t)(ar0 + rf)*32 + c0) << 9) + lane*8;
            ah[rf] = *(const bf16x8*)(AH + o);
            al[rf] = *(const bf16x8*)(AL + o);
        }
        #pragma unroll
        for (int n = 0; n < 4; ++n) {
            size_t o = (((size_t)(br0 + n)*32 + c0) << 9) + lane*8;
            bh_[n] = *(const bf16x8*)(BH + o);
            bl[n]  = *(const bf16x8*)(BL + o);
        }
        #pragma unroll
        for (int rf = 0; rf < 4; ++rf)
            #pragma unroll
            for (int n = 0; n < 4; ++n) {
                acc[rf][n] = mfma16(al[rf], bh_[n], acc[rf][n]);
                acc[rf][n] = mfma16(ah[rf], bl[n],  acc[rf][n]);
                acc[rf][n] = mfma16(ah[rf], bh_[n], acc[rf][n]);
            }
    }

    // epilogue
    #pragma unroll
    for (int n = 0; n < 4; ++n) {
        int col = m0 + wc*64 + n*16 + lr;
        float bb = bias[col];
        #pragma unroll
        for (int rf = 0; rf < 4; ++rf)
            #pragma unroll
            for (int r = 0; r < 4; ++r) {
                float v = acc[rf][n][r] + bb;
                int trow = n0 + wr*64 + rf*16 + lg*4 + r;
                if (MODE == 1) {
                    outf[(size_t)trow*1024 + col] = v;
                } else {
                    int js = col >> 10;
                    int hh = (col >> 6) & 15;
                    int dd = col & 63;
                    int b  = trow >> 10, t = trow & 1023;
                    int bh = b*16 + hh;
                    __bf16 bv = (__bf16)v;
                    if (js == 0)      Qb [((size_t)bh*1024 + t)*64 + dd] = bv;
                    else if (js == 1) Kb [((size_t)bh*1024 + t)*64 + dd] = bv;
                    else              Vtb[((size_t)bh*64 + dd)*1024 + t] = bv;
                }
            }
    }
}

// ---------------------------------------------------------------- scratch projections (f32 math, bf16 out)
__global__ __launch_bounds__(256) void k_sproj(const float* __restrict__ sin_,
        const float* __restrict__ Wq, const float* __restrict__ Wk, const float* __restrict__ Wv,
        __bf16* __restrict__ Qsb, __bf16* __restrict__ Ksb, __bf16* __restrict__ Vstb)
{
    __shared__ float inT[64*132];
    __shared__ float Wt[64*68];
    const int tid = threadIdx.x;
    const int tx = tid & 15, ty = tid >> 4;
    const int bh = blockIdx.y;
    const int h  = bh & (NH_-1);
    const int t0 = blockIdx.x * 128;
    const size_t base = ((size_t)bh * T_ + t0) * 64;

    #pragma unroll
    for (int l = 0; l < 8; ++l) {
        int fid = l*256 + tid;
        int row = fid >> 4, c4 = fid & 15;
        f4 a = *(const f4*)&sin_[base + (size_t)row*64 + c4*4];
        #pragma unroll
        for (int j = 0; j < 4; ++j) inT[(c4*4+j)*132 + row] = a[j];
    }

    for (int w = 0; w < 3; ++w) {
        const float* Wp = (w == 0) ? Wq : ((w == 1) ? Wk : Wv);
        __syncthreads();
        #pragma unroll
        for (int l = 0; l < 4; ++l) {
            int fid = l*256 + tid;
            int s = fid >> 4, c4 = fid & 15;
            *(f4*)&Wt[s*68 + c4*4] = *(const f4*)&Wp[(size_t)h*4096 + s*64 + c4*4];
        }
        __syncthreads();
        float acc[8][4] = {};
        #pragma unroll 8
        for (int s = 0; s < 64; ++s) {
            f4 w4 = *(const f4*)&Wt[s*68 + tx*4];
            f4 a0 = *(const f4*)&inT[s*132 + ty*8];
            f4 a1 = *(const f4*)&inT[s*132 + ty*8 + 4];
            #pragma unroll
            for (int r = 0; r < 4; ++r)
                #pragma unroll
                for (int j = 0; j < 4; ++j) {
                    acc[r][j]   += a0[r]*w4[j];
                    acc[4+r][j] += a1[r]*w4[j];
                }
        }
        if (w < 2) {
            __bf16* Op = (w == 0) ? Qsb : Ksb;
            #pragma unroll
            for (int r = 0; r < 8; ++r) {
                bf16x4 v;
                #pragma unroll
                for (int j = 0; j < 4; ++j) v[j] = (__bf16)acc[r][j];
                *(bf16x4*)&Op[base + (size_t)(ty*8+r)*64 + tx*4] = v;
            }
        } else {
            #pragma unroll
            for (int r = 0; r < 8; ++r)
                #pragma unroll
                for (int j = 0; j < 4; ++j)
                    Vstb[((size_t)bh*64 + tx*4+j)*1024 + t0 + ty*8 + r] = (__bf16)acc[r][j];
        }
    }
}

// ---------------------------------------------------------------- MFMA flash attention + stats
// QTILE=64 (4 waves x 16 rows), KTILE=64. All operands bf16 in global.
// 2-phase pipeline: K/Ks/V/Vs double-buffered in LDS; tile t+1's global_load_lds
// issued BEFORE tile t's compute; ONE barrier per tile.
// Epilogue: ctx emitted as hi/lo bf16 split in FRAGMENT-TILED layout for oproj.
__global__ __launch_bounds__(256, 2) void k_attn(
        const __bf16* __restrict__ Qcb, const __bf16* __restrict__ Kcb, const __bf16* __restrict__ Vtb,
        const __bf16* __restrict__ Qsb, const __bf16* __restrict__ Ksb, const __bf16* __restrict__ Vstb,
        const float* __restrict__ lam, const float* __restrict__ phv,
        __bf16* __restrict__ ctxH, __bf16* __restrict__ ctxL,
        float* __restrict__ out2, float* __restrict__ accum)
{
    __shared__ __bf16 sKC[2][4096];   // [64 key][64 d], chunk-XOR swizzled
    __shared__ __bf16 sKS[2][4096];
    __shared__ __bf16 sVC[2][4096];   // [64 d][64 key]  (from Vtb)
    __shared__ __bf16 sVS[2][4096];
    __shared__ __bf16 sP [4096];      // [64 qrow][64 key], wave-local strips

    const int tid  = threadIdx.x;
    const int lane = tid & 63;
    const int wid  = tid >> 6;
    const int lr   = lane & 15;
    const int lg   = lane >> 4;
    const int bh   = blockIdx.x;          // 0..63
    const int qt   = 15 - blockIdx.y;     // reversed: heavy blocks first
    const int h    = bh & (NH_-1);
    const int b    = bh >> 4;
    const int q0   = qt * 64;

    const float lv   = lam[0];
    const float coef = (lv > 1e-8f ? lv : 0.f) * __expf(phv[h]);

    const char* kcB = (const char*)Kcb  + (size_t)bh*1024*128;
    const char* ksB = (const char*)Ksb  + (size_t)bh*1024*128;
    const char* vtB = (const char*)Vtb  + (size_t)bh*64*2048;
    const char* vsB = (const char*)Vstb + (size_t)bh*64*2048;

    // staging addressing (per-lane, constant across tiles)
    const int strow0 = wid*16 + (lane>>3);        // c=0 row; c=1 adds 8
    const size_t dsto0 = (size_t)wid*2048;        // c=0 dst;  c=1 adds 1024

    auto STAGE = [&](int kt, int buf) {
        const bool pvn = (kt <= qt);
        #pragma unroll
        for (int c = 0; c < 2; ++c) {
            int trow = strow0 + c*8;
            int sc_  = (lane&7) ^ (trow&7);
            size_t dsto = dsto0 + c*1024;
            gld16(kcB + ((size_t)(kt*64 + trow))*128 + sc_*16, (char*)sKC[buf] + dsto);
            gld16(ksB + ((size_t)(kt*64 + trow))*128 + sc_*16, (char*)sKS[buf] + dsto);
            if (pvn) {
                gld16(vtB + (size_t)trow*2048 + kt*128 + sc_*16, (char*)sVC[buf] + dsto);
                gld16(vsB + (size_t)trow*2048 + kt*128 + sc_*16, (char*)sVS[buf] + dsto);
            }
        }
    };

    // Q fragments direct from global bf16
    bf16x8 qcf[2], qsf[2];
    {
        int row = q0 + wid*16 + lr;
        size_t qb = ((size_t)bh*1024 + row)*64;
        #pragma unroll
        for (int hf = 0; hf < 2; ++hf) {
            qcf[hf] = *(const bf16x8*)&Qcb[qb + hf*32 + lg*8];
            qsf[hf] = *(const bf16x8*)&Qsb[qb + hf*32 + lg*8];
        }
    }

    f32x4 Oc[4], Os[4];
    #pragma unroll
    for (int n = 0; n < 4; ++n) { Oc[n] = (f32x4){0,0,0,0}; Os[n] = (f32x4){0,0,0,0}; }

    float m4[4], l4[4];
    float sc_s[4] = {}, qq_c[4] = {}, ss_s[4] = {}, qq_s[4] = {};
    #pragma unroll
    for (int i = 0; i < 4; ++i) { m4[i] = -INFINITY; l4[i] = 0.f; }

    // prologue: stage tile 0, drain, then pipeline
    STAGE(0, 0);
    __syncthreads();

    int cur = 0;
    for (int kt = 0; kt < 16; ++kt) {
        const bool pv = (kt <= qt);
        // ---- issue next tile's loads into the alternate buffer
        if (kt < 15) STAGE(kt + 1, cur ^ 1);

        // ---- S = Q K^T both streams + stats (reads buffer `cur`)
        float L[4][4];   // [n][r]
        #pragma unroll
        for (int n = 0; n < 4; ++n) {
            int krow = n*16 + lr;
            int rswz = krow & 7;
            const char* pc = (const char*)sKC[cur] + krow*128;
            const char* ps = (const char*)sKS[cur] + krow*128;
            bf16x8 kc0 = *(const bf16x8*)(pc + (((lg  ) ^ rswz)<<4));
            bf16x8 kc1 = *(const bf16x8*)(pc + (((lg+4) ^ rswz)<<4));
            bf16x8 ks0 = *(const bf16x8*)(ps + (((lg  ) ^ rswz)<<4));
            bf16x8 ks1 = *(const bf16x8*)(ps + (((lg+4) ^ rswz)<<4));
            f32x4 z = {0.f,0.f,0.f,0.f};
            f32x4 sc = mfma16(qcf[1], kc1, mfma16(qcf[0], kc0, z));
            f32x4 ss = mfma16(qsf[1], ks1, mfma16(qsf[0], ks0, z));
            #pragma unroll
            for (int r = 0; r < 4; ++r) {
                sc_s[r] += sc[r];
                qq_c[r] = fmaf(sc[r], sc[r], qq_c[r]);
                ss_s[r] += ss[r];
                qq_s[r] = fmaf(ss[r], ss[r], qq_s[r]);
                L[n][r] = 0.125f * fmaf(coef, ss[r], sc[r]);
            }
        }

        if (pv) {
            // ---- causal mask on diagonal tile
            if (kt == qt) {
                #pragma unroll
                for (int n = 0; n < 4; ++n) {
                    int kc = n*16 + lr;
                    #pragma unroll
                    for (int r = 0; r < 4; ++r)
                        if (kc > wid*16 + lg*4 + r) L[n][r] = -INFINITY;
                }
            }

            // ---- online softmax (rows = lg*4+r, cols split across 16 lr-lanes)
            float fr4[4];
            #pragma unroll
            for (int r = 0; r < 4; ++r) {
                float v = fmaxf(fmaxf(L[0][r], L[1][r]), fmaxf(L[2][r], L[3][r]));
                v = fmaxf(v, __shfl_xor(v, 1));
                v = fmaxf(v, __shfl_xor(v, 2));
                v = fmaxf(v, __shfl_xor(v, 4));
                v = fmaxf(v, __shfl_xor(v, 8));
                float mn = fmaxf(m4[r], v);
                float fr = __expf(m4[r] - mn);
                m4[r] = mn; fr4[r] = fr;
                float ps = 0.f;
                #pragma unroll
                for (int n = 0; n < 4; ++n) {
                    float p = __expf(L[n][r] - mn);
                    L[n][r] = p;
                    ps += p;
                }
                l4[r] = l4[r]*fr + ps;
            }
            #pragma unroll
            for (int n = 0; n < 4; ++n)
                #pragma unroll
                for (int r = 0; r < 4; ++r) {
                    Oc[n][r] *= fr4[r];
                    Os[n][r] *= fr4[r];
                }

            // ---- P -> wave-local LDS strip (bf16, swizzled)
            #pragma unroll
            for (int n = 0; n < 4; ++n)
                #pragma unroll
                for (int r = 0; r < 4; ++r) {
                    int prow = wid*16 + lg*4 + r;
                    *((__bf16*)((char*)sP + prow*128 + ((((n*16+lr)>>3) ^ (prow&7))<<4) + (((n*16+lr)&7)<<1))) = (__bf16)L[n][r];
                }

            // ---- O += P V (both streams)
            bf16x8 pa[2];
            {
                int prow = wid*16 + lr;
                const char* pp = (const char*)sP + prow*128;
                pa[0] = *(const bf16x8*)(pp + (((lg  ) ^ (prow&7))<<4));
                pa[1] = *(const bf16x8*)(pp + (((lg+4) ^ (prow&7))<<4));
            }
            #pragma unroll
            for (int n = 0; n < 4; ++n) {
                int vrow = n*16 + lr;
                int rswz = vrow & 7;
                const char* pc = (const char*)sVC[cur] + vrow*128;
                const char* ps = (const char*)sVS[cur] + vrow*128;
                bf16x8 vc0 = *(const bf16x8*)(pc + (((lg  ) ^ rswz)<<4));
                bf16x8 vc1 = *(const bf16x8*)(pc + (((lg+4) ^ rswz)<<4));
                bf16x8 vs0 = *(const bf16x8*)(ps + (((lg  ) ^ rswz)<<4));
                bf16x8 vs1 = *(const bf16x8*)(ps + (((lg+4) ^ rswz)<<4));
                Oc[n] = mfma16(pa[1], vc1, mfma16(pa[0], vc0, Oc[n]));
                Os[n] = mfma16(pa[1], vs1, mfma16(pa[0], vs0, Os[n]));
            }
        }

        // ---- one barrier per tile: drains next-tile loads (covered by compute)
        // and fences all waves' reads of buffer `cur`
        __syncthreads();
        cur ^= 1;
    }

    // ---- d2 partial (per-lane cols are disjoint)
    float d2p = qq_s[0] + qq_s[1] + qq_s[2] + qq_s[3];

    // ---- reduce row stats across 16 lr-lanes
    #pragma unroll
    for (int r = 0; r < 4; ++r) {
        #pragma unroll
        for (int msk = 1; msk <= 8; msk <<= 1) {
            l4[r]   += __shfl_xor(l4[r],   msk);
            sc_s[r] += __shfl_xor(sc_s[r], msk);
            qq_c[r] += __shfl_xor(qq_c[r], msk);
            ss_s[r] += __shfl_xor(ss_s[r], msk);
            qq_s[r] += __shfl_xor(qq_s[r], msk);
        }
    }

    // ---- outputs: ctx as hi/lo bf16 split in FRAGMENT-TILED layout; out2 f32
    // logical row (n-dim) = b*1024 + q0 + wid*16 + lg*4 + r ; col (k-dim) = h*64 + n*16 + lr
    const int rtile = (b << 6) + (qt << 2) + wid;    // (b*1024+q0+wid*16)>>4
    #pragma unroll
    for (int r = 0; r < 4; ++r) {
        float linv = 1.0f / l4[r];
        int row = q0 + wid*16 + lg*4 + r;
        #pragma unroll
        for (int n = 0; n < 4; ++n) {
            int d = n*16 + lr;
            float oc = Oc[n][r] * linv;
            int col = h*64 + d;
            int c0   = col >> 5;
            int lgp  = (col >> 3) & 3;
            int lanep = lgp*16 + lg*4 + r;
            size_t off = (((size_t)rtile*32 + c0) << 9) + lanep*8 + (col & 7);
            __bf16 hv = (__bf16)oc;
            ctxH[off] = hv;
            ctxL[off] = (__bf16)(oc - (float)hv);
            out2[((size_t)bh*T_ + row)*64 + d] = Os[n][r] * linv;
        }
    }

    // ---- row-std ratios (rows replicated on 16 lanes -> 1/16 weight)
    float rp = 0.f;
    #pragma unroll
    for (int r = 0; r < 4; ++r) {
        float S1c = 0.125f    * sc_s[r];
        float S2c = 0.015625f * qq_c[r];
        float S1s = 0.125f    * ss_s[r];
        float S2s = 0.015625f * qq_s[r];
        float varc = (S2c - S1c*S1c*(1.f/1024.f)) * (1.f/1023.f);
        float vars = (S2s - S1s*S1s*(1.f/1024.f)) * (1.f/1023.f);
        rp += sqrtf(fmaxf(vars, 0.f)) / (sqrtf(fmaxf(varc, 0.f)) + 1e-6f);
    }
    rp *= (1.f/16.f);

    #pragma unroll
    for (int msk = 1; msk <= 32; msk <<= 1) {
        d2p += __shfl_xor(d2p, msk);
        rp  += __shfl_xor(rp,  msk);
    }
    __syncthreads();                      // all waves done with LDS
    float* sred = (float*)sP;
    if (lane == 0) { sred[wid] = d2p; sred[4+wid] = rp; }
    __syncthreads();
    if (tid == 0) {
        float td2 = (sred[0]+sred[1]+sred[2]+sred[3]) * coef * coef * 0.015625f;
        float tr  =  sred[4]+sred[5]+sred[6]+sred[7];
        atomicAdd(&accum[0], td2);
        atomicAdd(&accum[1], tr);
    }
}

// ---------------------------------------------------------------- finalize scalars
__global__ void k_fin(const float* __restrict__ acc, float* __restrict__ out) {
    if (threadIdx.x == 0) {
        out[0] = sqrtf(acc[0] * (1.f/67108864.f));   // / (B*NH*T*T)
        out[1] = acc[1] * (1.f/65536.f);             // / (B*NH*T)
    }
}

extern "C" void kernel_launch(void* const* d_in, const int* in_sizes, int n_in,
                              void* d_out, int out_size, void* d_ws, size_t ws_size,
                              hipStream_t stream)
{
    const float* data  = (const float*)d_in[0];
    const float* sin_  = (const float*)d_in[1];
    const float* qkv_w = (const float*)d_in[2];
    const float* qkv_b = (const float*)d_in[3];
    const float* out_w = (const float*)d_in[4];
    const float* out_b = (const float*)d_in[5];
    const float* Wq    = (const float*)d_in[6];
    const float* Wk    = (const float*)d_in[7];
    const float* Wv    = (const float*)d_in[8];
    const float* lam   = (const float*)d_in[9];
    const float* phv   = (const float*)d_in[10];
    float* out = (float*)d_out;
    char*  w   = (char*)d_ws;

    const size_t MB = 1024*1024;
    __bf16* Qcb   = (__bf16*)(w);             // 8 MB each
    __bf16* Kcb   = (__bf16*)(w + 8*MB);
    __bf16* Vtb   = (__bf16*)(w + 16*MB);
    __bf16* Qsb   = (__bf16*)(w + 24*MB);
    __bf16* Ksb   = (__bf16*)(w + 32*MB);
    __bf16* Vstb  = (__bf16*)(w + 40*MB);
    __bf16* dataH = (__bf16*)(w + 48*MB);     // tiled; aliased as ctxH after qkv GEMM
    __bf16* dataL = (__bf16*)(w + 56*MB);     // tiled; aliased as ctxL
    __bf16* wH    = (__bf16*)(w + 64*MB);     // 6 MB each (tiled)
    __bf16* wL    = (__bf16*)(w + 70*MB);
    __bf16* owH   = (__bf16*)(w + 76*MB);     // 2 MB each (tiled)
    __bf16* owL   = (__bf16*)(w + 78*MB);
    float*  accum = (float*)(w + 80*MB);

    k_zero   <<<1, 64, 0, stream>>>(accum);
    k_split  <<<2048, 256, 0, stream>>>(data, dataH, dataL, qkv_w, wH, wL, out_w, owH, owL);
    k_gemm<0><<<dim3(24, 32), 256, 0, stream>>>(dataH, dataL, wH, wL, qkv_b, Qcb, Kcb, Vtb, nullptr);
    k_sproj  <<<dim3(8, 64), 256, 0, stream>>>(sin_, Wq, Wk, Wv, Qsb, Ksb, Vstb);
    k_attn   <<<dim3(64, 16), 256, 0, stream>>>(Qcb, Kcb, Vtb, Qsb, Ksb, Vstb, lam, phv,
                                                dataH, dataL, out + (size_t)MSZ, accum);
    k_gemm<1><<<dim3(8, 32), 256, 0, stream>>>(dataH, dataL, owH, owL, out_b, nullptr, nullptr, nullptr, out);
    k_fin    <<<1, 64, 0, stream>>>(accum, out + 2*(size_t)MSZ);
}